// Round 2
// baseline (24815.828 us; speedup 1.0000x reference)
//
#include <hip/hip_runtime.h>
#include <cstdint>
#include <cmath>

// ---------------- dims ----------------
#define NB    64      // batch
#define EMBD  300
#define EMBP  320     // padded K for embedding-side GEMMs
#define EH    512     // encoder hidden
#define DH    1024    // decoder hidden
#define GV    23262   // target vocab
#define GVP   23296   // padded to 182*128
#define TSRC  50
#define TDEC  49      // decoder steps

typedef __attribute__((ext_vector_type(8))) short bf16x8;
typedef __attribute__((ext_vector_type(4))) float f32x4;

__device__ __forceinline__ unsigned short f2b(float f){
  union { float f; uint32_t u; } v; v.f = f;
  uint32_t u = (v.u + 0x7fffu + ((v.u >> 16) & 1u)) >> 16;
  return (unsigned short)u;
}
__device__ __forceinline__ float b2f(unsigned short h){
  union { uint32_t u; float f; } v; v.u = ((uint32_t)h) << 16;
  return v.f;
}
__device__ __forceinline__ float sigm(float x){ return 1.f/(1.f+expf(-x)); }

// Accumulate acc[4][4] += A[64][K] @ W-rows^T using mfma_f32_16x16x32_bf16.
__device__ __forceinline__ void mmacc(f32x4 (&acc)[4][4],
    const unsigned short* __restrict__ A, int lda,
    const unsigned short* __restrict__ W, int ldw, int wkoff,
    int wr0, int wr1, int wr2, int wr3, int K, int lane)
{
  const int r = lane & 15, q = lane >> 4;
  const unsigned short* a0 = A + r*lda + q*8;
  const unsigned short* b0 = W + (size_t)(wr0 + r)*ldw + wkoff + q*8;
  const unsigned short* b1 = W + (size_t)(wr1 + r)*ldw + wkoff + q*8;
  const unsigned short* b2 = W + (size_t)(wr2 + r)*ldw + wkoff + q*8;
  const unsigned short* b3 = W + (size_t)(wr3 + r)*ldw + wkoff + q*8;
  for (int k = 0; k < K; k += 32) {
    bf16x8 a[4], b[4];
    a[0] = *(const bf16x8*)(a0 + k);
    a[1] = *(const bf16x8*)(a0 + 16*lda + k);
    a[2] = *(const bf16x8*)(a0 + 32*lda + k);
    a[3] = *(const bf16x8*)(a0 + 48*lda + k);
    b[0] = *(const bf16x8*)(b0 + k);
    b[1] = *(const bf16x8*)(b1 + k);
    b[2] = *(const bf16x8*)(b2 + k);
    b[3] = *(const bf16x8*)(b3 + k);
#pragma unroll
    for (int mi = 0; mi < 4; ++mi)
#pragma unroll
      for (int ni = 0; ni < 4; ++ni)
        acc[mi][ni] = __builtin_amdgcn_mfma_f32_16x16x32_bf16(a[mi], b[ni], acc[mi][ni], 0, 0, 0);
  }
}

// ---------------- prep kernels ----------------
__global__ void cvt_pad(const float* __restrict__ src, unsigned short* __restrict__ dst,
                        int rows, int scols, int dcols)
{
  int idx = blockIdx.x*256 + threadIdx.x;
  if (idx >= rows*dcols) return;
  int c = idx % dcols, rr = idx / dcols;
  dst[idx] = (c < scols) ? f2b(src[(size_t)rr*scols + c]) : (unsigned short)0;
}

// split fp32 -> hi + lo bf16 (hi = rn(v), lo = rn(v - hi)): ~fp32 precision via 3-pass MFMA
__global__ void cvt_split(const float* __restrict__ src,
                          unsigned short* __restrict__ hi, unsigned short* __restrict__ lo,
                          int rows, int scols, int dcols)
{
  int idx = blockIdx.x*256 + threadIdx.x;
  if (idx >= rows*dcols) return;
  int c = idx % dcols, rr = idx / dcols;
  float v = (c < scols) ? src[(size_t)rr*scols + c] : 0.f;
  unsigned short h = f2b(v);
  hi[idx] = h;
  lo[idx] = f2b(v - b2f(h));
}

__global__ void addb(const float* __restrict__ a, const float* __restrict__ b,
                     float* __restrict__ o, int n)
{
  int i = blockIdx.x*256 + threadIdx.x;
  if (i < n) o[i] = a[i] + b[i];
}

// src/trg embedding gather -> bf16, K padded to 320 with zeros. Also builds reversed x.
__global__ void k_embed(const int* __restrict__ src, const int* __restrict__ trg,
                        const float* __restrict__ eemb, const float* __restrict__ demb,
                        unsigned short* __restrict__ x_bf, unsigned short* __restrict__ xrev_bf,
                        unsigned short* __restrict__ pe_bf)
{
  int idx = blockIdx.x*256 + threadIdx.x;
  const int tot1 = TSRC*NB*EMBP;
  const int tot2 = TDEC*NB*EMBP;
  if (idx < tot1) {
    int e = idx % EMBP, rb = idx / EMBP;
    int t = rb >> 6, b = rb & 63;
    float v = 0.f;
    if (e < EMBD) v = eemb[(size_t)src[rb]*EMBD + e];
    unsigned short bv = f2b(v);
    x_bf[idx] = bv;
    xrev_bf[(size_t)((TSRC-1-t)*NB + b)*EMBP + e] = bv;
  } else if (idx < tot1 + tot2) {
    int k = idx - tot1;
    int e = k % EMBP, rb = k / EMBP;
    float v = 0.f;
    if (e < EMBD) v = demb[(size_t)trg[rb]*EMBD + e];
    pe_bf[k] = f2b(v);
  }
}

// ---------------- big tiled GEMM: out[M][N] = A[M][K](bf16) @ W[N][K]^T + bias ----------------
__global__ __launch_bounds__(256) void gemm128(
    const unsigned short* __restrict__ A, int lda,
    const unsigned short* __restrict__ W, int ldw,
    const float* __restrict__ bias,
    float* __restrict__ out, int ldo,
    int K, int mvalid, int nvalid, int rowoff)
{
  __shared__ unsigned short As[128*64];
  __shared__ unsigned short Bs[128*64];
  const int tid = threadIdx.x;
  const int m0 = blockIdx.y*128, n0 = blockIdx.x*128;
  const int w = tid >> 6, lane = tid & 63, r = lane & 15, q = lane >> 4;
  const int mw = (w >> 1)*64, nw = (w & 1)*64;
  f32x4 acc[4][4];
#pragma unroll
  for (int mi=0; mi<4; ++mi)
#pragma unroll
    for (int ni=0; ni<4; ++ni) acc[mi][ni] = 0.f;

  for (int kt = 0; kt < K; kt += 64) {
    bf16x8 ra[4], rb[4];
#pragma unroll
    for (int j = 0; j < 4; ++j) {
      int c = j*256 + tid, row = c >> 3, cc = c & 7;
      ra[j] = *(const bf16x8*)(A + (size_t)(m0+row)*lda + kt + cc*8);
      rb[j] = *(const bf16x8*)(W + (size_t)(n0+row)*ldw + kt + cc*8);
    }
    __syncthreads();
#pragma unroll
    for (int j = 0; j < 4; ++j) {
      int c = j*256 + tid, row = c >> 3, cc = c & 7;
      int sw = cc ^ (row & 7);
      *(bf16x8*)((char*)As + row*128 + (sw<<4)) = ra[j];
      *(bf16x8*)((char*)Bs + row*128 + (sw<<4)) = rb[j];
    }
    __syncthreads();
#pragma unroll
    for (int kk = 0; kk < 64; kk += 32) {
      int ch = (kk >> 3) + q;
      bf16x8 av[4], bv[4];
#pragma unroll
      for (int mi=0; mi<4; ++mi) {
        int row = mw + mi*16 + r;
        av[mi] = *(const bf16x8*)((char*)As + row*128 + ((ch ^ (row&7))<<4));
      }
#pragma unroll
      for (int ni=0; ni<4; ++ni) {
        int row = nw + ni*16 + r;
        bv[ni] = *(const bf16x8*)((char*)Bs + row*128 + ((ch ^ (row&7))<<4));
      }
#pragma unroll
      for (int mi=0; mi<4; ++mi)
#pragma unroll
        for (int ni=0; ni<4; ++ni)
          acc[mi][ni] = __builtin_amdgcn_mfma_f32_16x16x32_bf16(av[mi], bv[ni], acc[mi][ni], 0,0,0);
    }
  }
#pragma unroll
  for (int mi=0; mi<4; ++mi)
#pragma unroll
    for (int ni=0; ni<4; ++ni)
#pragma unroll
      for (int e=0; e<4; ++e) {
        int mrow = m0 + mw + mi*16 + q*4 + e;
        int col  = n0 + nw + ni*16 + r;
        if (mrow < mvalid && col < nvalid)
          out[(size_t)(mrow + rowoff)*ldo + col] = acc[mi][ni][e] + bias[col];
      }
}

// ---------------- encoder step (both dirs), gates+LSTM fused, split-precision h@Whh ----------------
__global__ __launch_bounds__(256) void enc_step(
    const unsigned short* __restrict__ whhFh, const unsigned short* __restrict__ whhFl,
    const unsigned short* __restrict__ whhRh, const unsigned short* __restrict__ whhRl,
    const unsigned short* __restrict__ hFiH, const unsigned short* __restrict__ hFiL,
    const unsigned short* __restrict__ hRiH, const unsigned short* __restrict__ hRiL,
    unsigned short* __restrict__ hFoH, unsigned short* __restrict__ hFoL,
    unsigned short* __restrict__ hRoH, unsigned short* __restrict__ hRoL,
    float* __restrict__ cF, float* __restrict__ cR,
    const float* __restrict__ xpF, const float* __restrict__ xpR,
    float* __restrict__ enc_out,
    unsigned short* __restrict__ dhH, unsigned short* __restrict__ dhL,
    float* __restrict__ dc,
    int t)
{
  const int dir = blockIdx.y;
  const unsigned short* Wh = dir ? whhRh : whhFh;
  const unsigned short* Wl = dir ? whhRl : whhFl;
  const unsigned short* Hh = dir ? hRiH : hFiH;
  const unsigned short* Hl = dir ? hRiL : hFiL;
  unsigned short* HoH = dir ? hRoH : hFoH;
  unsigned short* HoL = dir ? hRoL : hFoL;
  float* C = dir ? cR : cF;
  const float* XP = dir ? xpR : xpF;
  const int tid = threadIdx.x, w = tid >> 6, lane = tid & 63, r = lane & 15, q = lane >> 4;
  const int j0 = blockIdx.x*64 + w*16;
  f32x4 acc[4][4];
#pragma unroll
  for (int mi=0; mi<4; ++mi)
#pragma unroll
    for (int g=0; g<4; ++g)
#pragma unroll
      for (int e=0; e<4; ++e)
        acc[mi][g][e] = XP[(size_t)(t*NB + mi*16 + q*4 + e)*2048 + g*EH + j0 + r];
  mmacc(acc, Hh, EH, Wh, EH, 0, j0, EH + j0, 2*EH + j0, 3*EH + j0, EH, lane);
  mmacc(acc, Hh, EH, Wl, EH, 0, j0, EH + j0, 2*EH + j0, 3*EH + j0, EH, lane);
  mmacc(acc, Hl, EH, Wh, EH, 0, j0, EH + j0, 2*EH + j0, 3*EH + j0, EH, lane);
  const int erow = dir ? (TSRC-1 - t) : t;
#pragma unroll
  for (int mi=0; mi<4; ++mi)
#pragma unroll
    for (int e=0; e<4; ++e) {
      int b = mi*16 + q*4 + e;
      int j = j0 + r;
      float gi = acc[mi][0][e], gf = acc[mi][1][e], gg = acc[mi][2][e], go = acc[mi][3][e];
      float co = C[b*EH + j];
      float cn = sigm(gf)*co + sigm(gi)*tanhf(gg);
      float hn = sigm(go)*tanhf(cn);
      C[b*EH + j] = cn;
      unsigned short hb = f2b(hn);
      unsigned short lb = f2b(hn - b2f(hb));
      HoH[b*EH + j] = hb;
      HoL[b*EH + j] = lb;
      enc_out[(size_t)(erow*NB + b)*DH + dir*EH + j] = hn;
      if (t == TSRC-1) {
        dhH[b*DH + 2*j + dir] = hb;
        dhL[b*DH + 2*j + dir] = lb;
        dc[b*DH + 2*j + dir] = cn;
      }
    }
}

// ---------------- decoder: M1 = h @ [wi ; dec_Whh]^T -> qgh[64][5120] (split) ----------------
__global__ __launch_bounds__(256) void mm_m1(
    const unsigned short* __restrict__ dhH, const unsigned short* __restrict__ dhL,
    const unsigned short* __restrict__ wm1h, const unsigned short* __restrict__ wm1l,
    float* __restrict__ qgh)
{
  const int tid = threadIdx.x, w = tid >> 6, lane = tid & 63, r = lane & 15, q = lane >> 4;
  const int n0 = blockIdx.x*256 + w*64;
  f32x4 acc[4][4];
#pragma unroll
  for (int mi=0; mi<4; ++mi)
#pragma unroll
    for (int ni=0; ni<4; ++ni) acc[mi][ni] = 0.f;
  mmacc(acc, dhH, DH, wm1h, DH, 0, n0, n0+16, n0+32, n0+48, DH, lane);
  mmacc(acc, dhH, DH, wm1l, DH, 0, n0, n0+16, n0+32, n0+48, DH, lane);
  mmacc(acc, dhL, DH, wm1h, DH, 0, n0, n0+16, n0+32, n0+48, DH, lane);
#pragma unroll
  for (int mi=0; mi<4; ++mi)
#pragma unroll
    for (int ni=0; ni<4; ++ni)
#pragma unroll
      for (int e=0; e<4; ++e)
        qgh[(size_t)(mi*16 + q*4 + e)*5120 + n0 + ni*16 + r] = acc[mi][ni][e];
}

// ---------------- attention: score/softmax/st per batch elem (fp32 enc_out) ----------------
__global__ __launch_bounds__(256) void att(
    const float* __restrict__ qgh, const float* __restrict__ enc_out,
    unsigned short* __restrict__ stH, unsigned short* __restrict__ stL)
{
  const int b = blockIdx.x, tid = threadIdx.x, w = tid >> 6, lane = tid & 63;
  __shared__ float sc[TSRC];
  for (int t = w; t < TSRC; t += 4) {
    const float* row = enc_out + (size_t)(t*NB + b)*DH + lane*16;
    const float* qp = qgh + (size_t)b*5120 + lane*16;
    float s = 0.f;
#pragma unroll
    for (int i=0;i<16;++i) s += row[i] * qp[i];
    for (int off=32; off; off>>=1) s += __shfl_down(s, off);
    if (lane == 0) sc[t] = s;
  }
  __syncthreads();
  float mx = -1e30f;
  for (int t=0;t<TSRC;++t) mx = fmaxf(mx, sc[t]);
  __syncthreads();
  if (tid < TSRC) sc[tid] = expf(sc[tid] - mx);
  __syncthreads();
  float sm = 0.f;
  for (int t=0;t<TSRC;++t) sm += sc[t];
  float inv = 1.f/sm;
  int c0 = tid*4;
  float a0=0,a1=0,a2=0,a3=0;
  for (int t=0;t<TSRC;++t) {
    const float* row = enc_out + (size_t)(t*NB + b)*DH + c0;
    float wt = sc[t]*inv;
    a0 += wt*row[0]; a1 += wt*row[1]; a2 += wt*row[2]; a3 += wt*row[3];
  }
  float av[4] = {a0,a1,a2,a3};
#pragma unroll
  for (int i=0;i<4;++i) {
    unsigned short hb = f2b(av[i]);
    stH[b*DH + c0 + i] = hb;
    stL[b*DH + c0 + i] = f2b(av[i] - b2f(hb));
  }
}

// ---------------- M2: ct = tanh([st, h] @ wo^T) (split) ----------------
__global__ __launch_bounds__(256) void mm_m2(
    const unsigned short* __restrict__ stH, const unsigned short* __restrict__ stL,
    const unsigned short* __restrict__ dhH, const unsigned short* __restrict__ dhL,
    const unsigned short* __restrict__ woh, const unsigned short* __restrict__ wol,
    unsigned short* __restrict__ ctH, unsigned short* __restrict__ ctL)
{
  const int tid = threadIdx.x, w = tid >> 6, lane = tid & 63, r = lane & 15, q = lane >> 4;
  const int n0 = blockIdx.x*256 + w*64;
  f32x4 acc[4][4];
#pragma unroll
  for (int mi=0; mi<4; ++mi)
#pragma unroll
    for (int ni=0; ni<4; ++ni) acc[mi][ni] = 0.f;
  mmacc(acc, stH, DH, woh, 2048, 0,    n0, n0+16, n0+32, n0+48, DH, lane);
  mmacc(acc, stH, DH, wol, 2048, 0,    n0, n0+16, n0+32, n0+48, DH, lane);
  mmacc(acc, stL, DH, woh, 2048, 0,    n0, n0+16, n0+32, n0+48, DH, lane);
  mmacc(acc, dhH, DH, woh, 2048, 1024, n0, n0+16, n0+32, n0+48, DH, lane);
  mmacc(acc, dhH, DH, wol, 2048, 1024, n0, n0+16, n0+32, n0+48, DH, lane);
  mmacc(acc, dhL, DH, woh, 2048, 1024, n0, n0+16, n0+32, n0+48, DH, lane);
#pragma unroll
  for (int mi=0; mi<4; ++mi)
#pragma unroll
    for (int ni=0; ni<4; ++ni)
#pragma unroll
      for (int e=0; e<4; ++e) {
        float v = tanhf(acc[mi][ni][e]);
        unsigned short hb = f2b(v);
        size_t ix = (size_t)(mi*16 + q*4 + e)*DH + n0 + ni*16 + r;
        ctH[ix] = hb;
        ctL[ix] = f2b(v - b2f(hb));
      }
}

// ---------------- M3: gates = ct@WihA^T + pe@WihB^T + gh + bias; LSTM update (split) ----------------
__global__ __launch_bounds__(256) void mm_m3(
    const unsigned short* __restrict__ ctH, const unsigned short* __restrict__ ctL,
    const unsigned short* __restrict__ pe_bf,
    const unsigned short* __restrict__ wih3h, const unsigned short* __restrict__ wih3l,
    const float* __restrict__ qgh,
    const float* __restrict__ bih, const float* __restrict__ bhh,
    float* __restrict__ dc,
    unsigned short* __restrict__ dhH, unsigned short* __restrict__ dhL,
    unsigned short* __restrict__ hdec, int t)
{
  const int tid = threadIdx.x, w = tid >> 6, lane = tid & 63, r = lane & 15, q = lane >> 4;
  const int j0 = blockIdx.x*64 + w*16;
  f32x4 acc[4][4];
#pragma unroll
  for (int mi=0; mi<4; ++mi)
#pragma unroll
    for (int g=0; g<4; ++g)
#pragma unroll
      for (int e=0; e<4; ++e) {
        int row = mi*16 + q*4 + e;
        int col = g*DH + j0 + r;
        acc[mi][g][e] = qgh[(size_t)row*5120 + 1024 + col] + bih[col] + bhh[col];
      }
  mmacc(acc, ctH, DH, wih3h, 1344, 0, j0, DH + j0, 2*DH + j0, 3*DH + j0, DH, lane);
  mmacc(acc, ctH, DH, wih3l, 1344, 0, j0, DH + j0, 2*DH + j0, 3*DH + j0, DH, lane);
  mmacc(acc, ctL, DH, wih3h, 1344, 0, j0, DH + j0, 2*DH + j0, 3*DH + j0, DH, lane);
  const unsigned short* pe = pe_bf + (size_t)t*NB*EMBP;
  mmacc(acc, pe, EMBP, wih3h, 1344, 1024, j0, DH + j0, 2*DH + j0, 3*DH + j0, EMBP, lane);
  mmacc(acc, pe, EMBP, wih3l, 1344, 1024, j0, DH + j0, 2*DH + j0, 3*DH + j0, EMBP, lane);
#pragma unroll
  for (int mi=0; mi<4; ++mi)
#pragma unroll
    for (int e=0; e<4; ++e) {
      int b = mi*16 + q*4 + e;
      int j = j0 + r;
      float gi = acc[mi][0][e], gf = acc[mi][1][e], gg = acc[mi][2][e], go = acc[mi][3][e];
      float co = dc[b*DH + j];
      float cn = sigm(gf)*co + sigm(gi)*tanhf(gg);
      float hn = sigm(go)*tanhf(cn);
      dc[b*DH + j] = cn;
      unsigned short hb = f2b(hn);
      dhH[b*DH + j] = hb;
      dhL[b*DH + j] = f2b(hn - b2f(hb));
      hdec[(size_t)(t*NB + b)*DH + j] = hb;
    }
}

// ---------------- in-place log-softmax over vocab rows ----------------
__global__ __launch_bounds__(256) void lsm(float* __restrict__ out)
{
  const int row = NB + blockIdx.x;  // rows 64..3199
  float* p = out + (size_t)row*GV;
  const int tid = threadIdx.x;
  __shared__ float red[4], red2[4];
  float mx = -1e30f;
  for (int i = tid; i < GV; i += 256) mx = fmaxf(mx, p[i]);
  for (int off=32; off; off>>=1) mx = fmaxf(mx, __shfl_down(mx, off));
  if ((tid & 63) == 0) red[tid>>6] = mx;
  __syncthreads();
  mx = fmaxf(fmaxf(red[0],red[1]), fmaxf(red[2],red[3]));
  float sm = 0.f;
  for (int i = tid; i < GV; i += 256) sm += expf(p[i] - mx);
  for (int off=32; off; off>>=1) sm += __shfl_down(sm, off);
  if ((tid & 63) == 0) red2[tid>>6] = sm;
  __syncthreads();
  sm = red2[0]+red2[1]+red2[2]+red2[3];
  float lse = mx + logf(sm);
  for (int i = tid; i < GV; i += 256) p[i] -= lse;
}

// ---------------- host ----------------
extern "C" void kernel_launch(void* const* d_in, const int* in_sizes, int n_in,
                              void* d_out, int out_size, void* d_ws, size_t ws_size,
                              hipStream_t stream)
{
  const int*   src  = (const int*)d_in[0];
  const int*   trg  = (const int*)d_in[1];
  const float* WihF = (const float*)d_in[2];
  const float* WhhF = (const float*)d_in[3];
  const float* bihF = (const float*)d_in[4];
  const float* bhhF = (const float*)d_in[5];
  const float* WihR = (const float*)d_in[6];
  const float* WhhR = (const float*)d_in[7];
  const float* bihR = (const float*)d_in[8];
  const float* bhhR = (const float*)d_in[9];
  const float* dWih = (const float*)d_in[10];
  const float* dWhh = (const float*)d_in[11];
  const float* dbih = (const float*)d_in[12];
  const float* dbhh = (const float*)d_in[13];
  const float* eemb = (const float*)d_in[14];
  const float* demb = (const float*)d_in[15];
  const float* wi   = (const float*)d_in[16];
  const float* wo   = (const float*)d_in[17];
  const float* genw = (const float*)d_in[18];
  const float* genb = (const float*)d_in[19];
  float* out = (float*)d_out;

  char* ws = (char*)d_ws;
  size_t off = 0;
  auto alloc = [&](size_t bytes)->char* {
    char* p = ws + off; off = (off + bytes + 255) & ~(size_t)255; return p;
  };
  unsigned short* x_bf    = (unsigned short*)alloc((size_t)TSRC*NB*EMBP*2);
  unsigned short* xrev_bf = (unsigned short*)alloc((size_t)TSRC*NB*EMBP*2);
  unsigned short* pe_bf   = (unsigned short*)alloc((size_t)TDEC*NB*EMBP*2);
  unsigned short* wihF_b  = (unsigned short*)alloc((size_t)2048*EMBP*2);
  unsigned short* wihR_b  = (unsigned short*)alloc((size_t)2048*EMBP*2);
  unsigned short* whhF_h  = (unsigned short*)alloc((size_t)2048*EH*2);
  unsigned short* whhF_l  = (unsigned short*)alloc((size_t)2048*EH*2);
  unsigned short* whhR_h  = (unsigned short*)alloc((size_t)2048*EH*2);
  unsigned short* whhR_l  = (unsigned short*)alloc((size_t)2048*EH*2);
  unsigned short* wm1_h   = (unsigned short*)alloc((size_t)5120*DH*2);
  unsigned short* wm1_l   = (unsigned short*)alloc((size_t)5120*DH*2);
  unsigned short* wo_h    = (unsigned short*)alloc((size_t)DH*2048*2);
  unsigned short* wo_l    = (unsigned short*)alloc((size_t)DH*2048*2);
  unsigned short* wih3_h  = (unsigned short*)alloc((size_t)4096*1344*2);
  unsigned short* wih3_l  = (unsigned short*)alloc((size_t)4096*1344*2);
  unsigned short* genw_b  = (unsigned short*)alloc((size_t)GVP*DH*2);
  float* b4f   = (float*)alloc(2048*4);
  float* b4r   = (float*)alloc(2048*4);
  float* xp_f  = (float*)alloc((size_t)TSRC*NB*2048*4);
  float* xp_r  = (float*)alloc((size_t)TSRC*NB*2048*4);
  float* enc_out = (float*)alloc((size_t)TSRC*NB*DH*4);
  unsigned short* hfh0 = (unsigned short*)alloc((size_t)NB*EH*2);
  unsigned short* hfl0 = (unsigned short*)alloc((size_t)NB*EH*2);
  unsigned short* hfh1 = (unsigned short*)alloc((size_t)NB*EH*2);
  unsigned short* hfl1 = (unsigned short*)alloc((size_t)NB*EH*2);
  unsigned short* hrh0 = (unsigned short*)alloc((size_t)NB*EH*2);
  unsigned short* hrl0 = (unsigned short*)alloc((size_t)NB*EH*2);
  unsigned short* hrh1 = (unsigned short*)alloc((size_t)NB*EH*2);
  unsigned short* hrl1 = (unsigned short*)alloc((size_t)NB*EH*2);
  float* cf = (float*)alloc((size_t)NB*EH*4);
  float* cr = (float*)alloc((size_t)NB*EH*4);
  unsigned short* dhH = (unsigned short*)alloc((size_t)NB*DH*2);
  unsigned short* dhL = (unsigned short*)alloc((size_t)NB*DH*2);
  float* dc = (float*)alloc((size_t)NB*DH*4);
  float* qgh = (float*)alloc((size_t)NB*5120*4);
  unsigned short* stH = (unsigned short*)alloc((size_t)NB*DH*2);
  unsigned short* stL = (unsigned short*)alloc((size_t)NB*DH*2);
  unsigned short* ctH = (unsigned short*)alloc((size_t)NB*DH*2);
  unsigned short* ctL = (unsigned short*)alloc((size_t)NB*DH*2);
  unsigned short* hdec  = (unsigned short*)alloc((size_t)3200*DH*2);
  (void)in_sizes; (void)n_in; (void)out_size; (void)ws_size;

  // --- init / zero state ---
  hipMemsetAsync(hfh0, 0, (size_t)NB*EH*2*4, stream);  // hfh0,hfl0,hfh1,hfl1 contiguous
  hipMemsetAsync(hrh0, 0, (size_t)NB*EH*2*4, stream);  // hrh0..hrl1
  hipMemsetAsync(cf,  0, (size_t)NB*EH*4, stream);
  hipMemsetAsync(cr,  0, (size_t)NB*EH*4, stream);
  hipMemsetAsync(hdec + (size_t)3136*DH, 0, (size_t)64*DH*2, stream);
  hipMemsetAsync(genw_b + (size_t)GV*DH, 0, (size_t)(GVP-GV)*DH*2, stream);
  hipMemsetAsync(out, 0, (size_t)NB*GV*4, stream);   // timestep 0 = zeros

  auto cgrid = [](size_t n){ return dim3((unsigned)((n + 255)/256)); };

  // --- weight conversion ---
  cvt_pad<<<cgrid((size_t)2048*EMBP),256,0,stream>>>(WihF, wihF_b, 2048, EMBD, EMBP);
  cvt_pad<<<cgrid((size_t)2048*EMBP),256,0,stream>>>(WihR, wihR_b, 2048, EMBD, EMBP);
  cvt_split<<<cgrid((size_t)2048*EH),256,0,stream>>>(WhhF, whhF_h, whhF_l, 2048, EH, EH);
  cvt_split<<<cgrid((size_t)2048*EH),256,0,stream>>>(WhhR, whhR_h, whhR_l, 2048, EH, EH);
  cvt_split<<<cgrid((size_t)1024*DH),256,0,stream>>>(wi, wm1_h, wm1_l, 1024, DH, DH);
  cvt_split<<<cgrid((size_t)4096*DH),256,0,stream>>>(dWhh, wm1_h + (size_t)1024*DH, wm1_l + (size_t)1024*DH, 4096, DH, DH);
  cvt_split<<<cgrid((size_t)DH*2048),256,0,stream>>>(wo, wo_h, wo_l, DH, 2048, 2048);
  cvt_split<<<cgrid((size_t)4096*1344),256,0,stream>>>(dWih, wih3_h, wih3_l, 4096, 1324, 1344);
  cvt_pad<<<cgrid((size_t)GV*DH),256,0,stream>>>(genw, genw_b, GV, DH, DH);
  addb<<<cgrid(2048),256,0,stream>>>(bihF, bhhF, b4f, 2048);
  addb<<<cgrid(2048),256,0,stream>>>(bihR, bhhR, b4r, 2048);
  k_embed<<<cgrid((size_t)(TSRC+TDEC)*NB*EMBP),256,0,stream>>>(src, trg, eemb, demb, x_bf, xrev_bf, pe_bf);

  // --- encoder input projections (both dirs) ---
  gemm128<<<dim3(16,25),256,0,stream>>>(x_bf,    EMBP, wihF_b, EMBP, b4f, xp_f, 2048, EMBP, 3200, 2048, 0);
  gemm128<<<dim3(16,25),256,0,stream>>>(xrev_bf, EMBP, wihR_b, EMBP, b4r, xp_r, 2048, EMBP, 3200, 2048, 0);

  // --- encoder recurrence ---
  for (int t = 0; t < TSRC; ++t) {
    const unsigned short* hfiH = (t & 1) ? hfh1 : hfh0;
    const unsigned short* hfiL = (t & 1) ? hfl1 : hfl0;
    const unsigned short* hriH = (t & 1) ? hrh1 : hrh0;
    const unsigned short* hriL = (t & 1) ? hrl1 : hrl0;
    unsigned short* hfoH = (t & 1) ? hfh0 : hfh1;
    unsigned short* hfoL = (t & 1) ? hfl0 : hfl1;
    unsigned short* hroH = (t & 1) ? hrh0 : hrh1;
    unsigned short* hroL = (t & 1) ? hrl0 : hrl1;
    enc_step<<<dim3(8,2),256,0,stream>>>(whhF_h, whhF_l, whhR_h, whhR_l,
                                         hfiH, hfiL, hriH, hriL,
                                         hfoH, hfoL, hroH, hroL,
                                         cf, cr, xp_f, xp_r, enc_out, dhH, dhL, dc, t);
  }

  // --- decoder recurrence ---
  for (int t = 0; t < TDEC; ++t) {
    mm_m1<<<20,256,0,stream>>>(dhH, dhL, wm1_h, wm1_l, qgh);
    att<<<NB,256,0,stream>>>(qgh, enc_out, stH, stL);
    mm_m2<<<4,256,0,stream>>>(stH, stL, dhH, dhL, wo_h, wo_l, ctH, ctL);
    mm_m3<<<16,256,0,stream>>>(ctH, ctL, pe_bf, wih3_h, wih3_l, qgh, dbih, dbhh, dc, dhH, dhL, hdec, t);
  }

  // --- generator: logits straight into d_out rows 64.. (t+1 shift), then log-softmax ---
  gemm128<<<dim3(GVP/128,25),256,0,stream>>>(hdec, DH, genw_b, DH, genb, out, GV, DH, 3136, GV, NB);
  lsm<<<3136,256,0,stream>>>(out);
}